// Round 1
// baseline (221.756 us; speedup 1.0000x reference)
//
#include <hip/hip_runtime.h>

#define MARGIN 1.0f

// ws[0] (double) is the global accumulator. Harness poisons d_ws once and never
// re-poisons between replays -> zero it ourselves every call.
__global__ void mcl_zero(double* __restrict__ ws) {
    if (threadIdx.x == 0 && blockIdx.x == 0) ws[0] = 0.0;
}

// One 256-thread block per row. Sum max(0, 1 + s - correct) over ALL c;
// the c==target term contributes exactly MARGIN, corrected in finalize.
__global__ __launch_bounds__(256) void mcl_hinge(const float* __restrict__ score,
                                                 const int* __restrict__ target,
                                                 double* __restrict__ ws,
                                                 int C) {
    const int row = blockIdx.x;
    const size_t base_idx = (size_t)row * (size_t)C;
    const int t = target[row];
    const float b = MARGIN - score[base_idx + t];   // broadcast load per block

    float acc = 0.0f;
    const int nvec = C >> 2;                        // 1250 float4 per row
    const float4* __restrict__ rp = reinterpret_cast<const float4*>(score + base_idx);
    for (int i = threadIdx.x; i < nvec; i += 256) {
        float4 v = rp[i];
        acc += fmaxf(0.0f, v.x + b);
        acc += fmaxf(0.0f, v.y + b);
        acc += fmaxf(0.0f, v.z + b);
        acc += fmaxf(0.0f, v.w + b);
    }
    // tail (C not divisible by 4) — empty for C=5000 but keep it general
    for (int i = (nvec << 2) + (int)threadIdx.x; i < C; i += 256)
        acc += fmaxf(0.0f, score[base_idx + i] + b);

    // 64-lane wave reduce
    #pragma unroll
    for (int off = 32; off > 0; off >>= 1)
        acc += __shfl_down(acc, off, 64);

    __shared__ float warp_s[4];
    const int lane = threadIdx.x & 63;
    const int wid  = threadIdx.x >> 6;
    if (lane == 0) warp_s[wid] = acc;
    __syncthreads();
    if (threadIdx.x == 0) {
        float bs = warp_s[0] + warp_s[1] + warp_s[2] + warp_s[3];
        atomicAdd(ws, (double)bs);   // device-scope, cross-XCD safe
    }
}

__global__ void mcl_final(const double* __restrict__ ws, float* __restrict__ out,
                          int N, int C) {
    if (threadIdx.x == 0 && blockIdx.x == 0) {
        // every row's c==target term contributed exactly MARGIN -> subtract N*MARGIN
        double s = ws[0] - (double)N * (double)MARGIN;
        out[0] = (float)(s / ((double)N * (double)(C - 1)));
    }
}

extern "C" void kernel_launch(void* const* d_in, const int* in_sizes, int n_in,
                              void* d_out, int out_size, void* d_ws, size_t ws_size,
                              hipStream_t stream) {
    const float* score  = (const float*)d_in[0];
    const int*   target = (const int*)d_in[1];
    float* out = (float*)d_out;
    double* ws = (double*)d_ws;

    const int N = in_sizes[1];
    const int C = in_sizes[0] / N;

    mcl_zero<<<1, 64, 0, stream>>>(ws);
    mcl_hinge<<<N, 256, 0, stream>>>(score, target, ws, C);
    mcl_final<<<1, 64, 0, stream>>>(ws, out, N, C);
}

// Round 2
// 59.178 us; speedup vs baseline: 3.7473x; 3.7473x over previous
//
#include <hip/hip_runtime.h>

#define MARGIN 1.0f
#define NBLOCKS 2048   // 8 blocks/CU x 256 CUs: one fully-resident generation

// Grid-stride over rows; per-block partial -> d_ws[blockIdx.x]. No atomics.
// The c==target term contributes exactly MARGIN per row; corrected in finalize.
__global__ __launch_bounds__(256) void mcl_hinge(const float* __restrict__ score,
                                                 const int* __restrict__ target,
                                                 double* __restrict__ partial,
                                                 int N, int C) {
    float acc = 0.0f;
    const int nvec = C >> 2;

    for (int row = blockIdx.x; row < N; row += gridDim.x) {
        const size_t base = (size_t)row * (size_t)C;
        // uniform (scalar) loads: target[row] then the correct-class score
        const float b = MARGIN - score[base + target[row]];
        const float4* __restrict__ rp = reinterpret_cast<const float4*>(score + base);
        for (int i = threadIdx.x; i < nvec; i += 256) {
            float4 v = rp[i];
            acc += fmaxf(0.0f, v.x + b);
            acc += fmaxf(0.0f, v.y + b);
            acc += fmaxf(0.0f, v.z + b);
            acc += fmaxf(0.0f, v.w + b);
        }
        for (int i = (nvec << 2) + (int)threadIdx.x; i < C; i += 256)
            acc += fmaxf(0.0f, score[base + i] + b);
    }

    // 64-lane wave reduce, then cross-wave via LDS
    #pragma unroll
    for (int off = 32; off > 0; off >>= 1)
        acc += __shfl_down(acc, off, 64);

    __shared__ float warp_s[4];
    const int lane = threadIdx.x & 63;
    const int wid  = threadIdx.x >> 6;
    if (lane == 0) warp_s[wid] = acc;
    __syncthreads();
    if (threadIdx.x == 0)
        partial[blockIdx.x] = (double)(warp_s[0] + warp_s[1] + warp_s[2] + warp_s[3]);
}

// One block reduces the NBLOCKS doubles and finalizes the mean.
__global__ __launch_bounds__(256) void mcl_final(const double* __restrict__ partial,
                                                 float* __restrict__ out,
                                                 int NB, int N, int C) {
    double s = 0.0;
    for (int i = threadIdx.x; i < NB; i += 256) s += partial[i];

    #pragma unroll
    for (int off = 32; off > 0; off >>= 1)
        s += __shfl_down(s, off, 64);

    __shared__ double warp_s[4];
    const int lane = threadIdx.x & 63;
    const int wid  = threadIdx.x >> 6;
    if (lane == 0) warp_s[wid] = s;
    __syncthreads();
    if (threadIdx.x == 0) {
        double tot = warp_s[0] + warp_s[1] + warp_s[2] + warp_s[3];
        tot -= (double)N * (double)MARGIN;              // remove c==target terms
        out[0] = (float)(tot / ((double)N * (double)(C - 1)));
    }
}

extern "C" void kernel_launch(void* const* d_in, const int* in_sizes, int n_in,
                              void* d_out, int out_size, void* d_ws, size_t ws_size,
                              hipStream_t stream) {
    const float* score  = (const float*)d_in[0];
    const int*   target = (const int*)d_in[1];
    float* out = (float*)d_out;
    double* ws = (double*)d_ws;   // NBLOCKS doubles = 16 KB of scratch

    const int N = in_sizes[1];
    const int C = in_sizes[0] / N;

    mcl_hinge<<<NBLOCKS, 256, 0, stream>>>(score, target, ws, N, C);
    mcl_final<<<1, 256, 0, stream>>>(ws, out, NBLOCKS, N, C);
}